// Round 8
// baseline (103.924 us; speedup 1.0000x reference)
//
#include <hip/hip_runtime.h>

// Diversity2: mean(0.3 * pearson_corr(softmax(o1/T), softmax(o2/T), axis=1))
//
// Identities:
//  (1) corr invariant to per-row positive scale+shift -> softmax drops out:
//      corr(p1,p2) == corr(exp(o1/T), exp(o2/T)).
//  (2) x = exp(o/T) - 1 (exact Sterbenz, exp in [0.78,1.32]) centers x near 0
//      -> fp32 accumulation of {Sx,Sy,Sxx,Syy,Sxy} has no catastrophic
//      cancellation. fp64 only in per-row epilogue + final mean.
//
// Round-8: r7 (best: 96.1 us) + ONE mechanism: finer dispatch granularity.
// 8192 blocks x 4 waves x 2 rows/wave; each wave issues ALL 16 dwordx4 loads
// (both row-pairs, 16 KB) before any use, then computes both rows. Block
// work drops 256 KB -> 64 KB (4x finer), so the hardware dispatcher
// rebalances the L3-hit/HBM-miss luck across CUs (r3 proved the inverse
// direction: coarser grid -> -16%). Two-kernel finish kept (r6: fused
// single-counter finish costs +95 us in serialized ACQ_REL RMWs).
//
// Pre-committed read: <=93 keep iterating; >=95 with FETCH unchanged ->
// all four in-flight/balance mechanisms exhausted at ~92% of the measured
// 6.29 TB/s streaming ceiling -> declare roofline.
//
// Tail: row = 1000 floats = 250 float4; chunk 3 valid lanes<58. Lanes >=58
// read float4 index 0 (in-bounds), inputs zeroed at consume (exp(0)-1 == 0).

#define N_ROWS  65536
#define N_C     1000
#define WPB     4

__device__ __forceinline__ const float4* rp(const float* o, int row) {
    return reinterpret_cast<const float4*>(o + (long)row * N_C);
}

__device__ __forceinline__ void accum_row(
        float4 a0, float4 a1, float4 a2, float4 a3,
        float4 b0, float4 b1, float4 b2, float4 b3,
        bool tail_ok, double& acc) {
    constexpr float INV_T = 1.0f / 20.0f;
    float sx = 0.f, sy = 0.f, sxx = 0.f, syy = 0.f, sxy = 0.f;
    float va[16] = {a0.x, a0.y, a0.z, a0.w, a1.x, a1.y, a1.z, a1.w,
                    a2.x, a2.y, a2.z, a2.w, a3.x, a3.y, a3.z, a3.w};
    float vb[16] = {b0.x, b0.y, b0.z, b0.w, b1.x, b1.y, b1.z, b1.w,
                    b2.x, b2.y, b2.z, b2.w, b3.x, b3.y, b3.z, b3.w};
    #pragma unroll
    for (int e = 0; e < 16; ++e) {
        const bool ok = (e < 12) || tail_ok;    // compile-time e
        float fa = ok ? va[e] : 0.0f;           // static index (rule #20)
        float fb = ok ? vb[e] : 0.0f;
        float x = __expf(fa * INV_T) - 1.0f;
        float y = __expf(fb * INV_T) - 1.0f;
        sx += x;  sy += y;
        sxx = fmaf(x, x, sxx);
        syy = fmaf(y, y, syy);
        sxy = fmaf(x, y, sxy);
    }
    #pragma unroll
    for (int off = 32; off; off >>= 1) {
        sx  += __shfl_xor(sx,  off, 64);
        sy  += __shfl_xor(sy,  off, 64);
        sxx += __shfl_xor(sxx, off, 64);
        syy += __shfl_xor(syy, off, 64);
        sxy += __shfl_xor(sxy, off, 64);
    }
    constexpr double invC = 1.0 / (double)N_C;
    double dx = (double)sx, dy = (double)sy;
    double num = (double)sxy - dx * dy * invC;
    double vx  = (double)sxx - dx * dx * invC;
    double vy  = (double)syy - dy * dy * invC;
    acc += num / sqrt(vx * vy);
}

// Each wave handles `batches` 2-row batches; rows of one batch are gw and
// gw + nwaves (adjacent strides), batches step by 2*nwaves.
__global__ __launch_bounds__(256) void div2_stage1(
        const float* __restrict__ o1, const float* __restrict__ o2,
        double* __restrict__ ws, int batches) {
    const int wave   = threadIdx.x >> 6;
    const int lane   = threadIdx.x & 63;
    const int nwaves = gridDim.x * WPB;
    const int gw     = blockIdx.x * WPB + wave;
    const int i3     = (lane < 58) ? (192 + lane) : 0;   // clamped chunk-3 idx
    const bool tail_ok = (lane < 58);

    double acc = 0.0;
    #pragma unroll 1
    for (int b = 0; b < batches; ++b) {
        const int r0 = gw + b * 2 * nwaves;
        const int r1 = r0 + nwaves;
        // all 16 loads (both row-pairs, 16 KB) issued before any use
        const float4* A0 = rp(o1, r0);
        const float4* B0 = rp(o2, r0);
        const float4* A1 = rp(o1, r1);
        const float4* B1 = rp(o2, r1);
        float4 pa0 = A0[lane], pa1 = A0[64 + lane], pa2 = A0[128 + lane], pa3 = A0[i3];
        float4 pb0 = B0[lane], pb1 = B0[64 + lane], pb2 = B0[128 + lane], pb3 = B0[i3];
        float4 qa0 = A1[lane], qa1 = A1[64 + lane], qa2 = A1[128 + lane], qa3 = A1[i3];
        float4 qb0 = B1[lane], qb1 = B1[64 + lane], qb2 = B1[128 + lane], qb3 = B1[i3];
        accum_row(pa0, pa1, pa2, pa3, pb0, pb1, pb2, pb3, tail_ok, acc);
        accum_row(qa0, qa1, qa2, qa3, qb0, qb1, qb2, qb3, tail_ok, acc);
    }

    __shared__ double dred[WPB];
    if (lane == 0) dred[wave] = acc;
    __syncthreads();
    if (threadIdx.x == 0)
        ws[blockIdx.x] = dred[0] + dred[1] + dred[2] + dred[3];
}

__global__ __launch_bounds__(256) void div2_stage2(
        const double* __restrict__ ws, int n, float* __restrict__ out) {
    double s = 0.0;
    for (int i = threadIdx.x; i < n; i += 256) s += ws[i];
    #pragma unroll
    for (int off = 32; off; off >>= 1) s += __shfl_xor(s, off, 64);
    __shared__ double lds[4];
    const int wave = threadIdx.x >> 6;
    const int lane = threadIdx.x & 63;
    if (lane == 0) lds[wave] = s;
    __syncthreads();
    if (threadIdx.x == 0) {
        double t = lds[0] + lds[1] + lds[2] + lds[3];
        out[0] = (float)(t * (0.3 / (double)N_ROWS));
    }
}

extern "C" void kernel_launch(void* const* d_in, const int* in_sizes, int n_in,
                              void* d_out, int out_size, void* d_ws, size_t ws_size,
                              hipStream_t stream) {
    const float* o1 = (const float*)d_in[0];
    const float* o2 = (const float*)d_in[1];
    // d_in[2] (targets) is unused by the reference.
    float* out = (float*)d_out;
    double* ws = (double*)d_ws;

    // Prefer 8192 blocks (2 rows/wave, finest balance); fall back to 2048
    // blocks (8 rows/wave) if d_ws can't hold 8192 fp64 partials.
    int nblocks = 8192, batches = 1;
    if (ws_size < (size_t)nblocks * sizeof(double)) { nblocks = 2048; batches = 4; }

    div2_stage1<<<nblocks, 256, 0, stream>>>(o1, o2, ws, batches);
    div2_stage2<<<1, 256, 0, stream>>>(ws, nblocks, out);
}